// Round 1
// 270.744 us; speedup vs baseline: 1.0022x; 1.0022x over previous
//
#include <hip/hip_runtime.h>
#include <stdint.h>

// PCLayer closed form, single-big-GEMM route:
//   E   = lr * W^T W                      [768,768]   (split-K partials + reduce)
//   S'' = -45E + 120E^2                               (E^3 term < 1e-5; validated)
//   WMT = 0.01*W^T + lr * S'' @ W^T       [768,3072]  (small GEMM, EPI=3)
//   out = (t - b) @ WMT^T                 [8192,768]  (ONE big GEMM, fp32 out)
// Rationale: S'' symmetric => out = y @ (0.01 I + lr S'') folds GEMM2 into the
// weights; deletes yb (12.6MB write + 25MB reads) and one ~60us dispatch.
// Big GEMM at TM=64: grid 128x6=768 blocks = 3 blocks/CU (was 384 = 1.5/CU,
// Occupancy 14% -> barrier drains unhidden; m102 curve says 3-4/CU ~ 800 TF).
// All GEMMs: m97 gl2lds+LDS structure, BK=64 (r5-proven).

typedef short bf16x8 __attribute__((ext_vector_type(8)));   // 8 bf16 = 4 VGPRs
typedef float f32x4  __attribute__((ext_vector_type(4)));
typedef unsigned short u16;
typedef unsigned int uint_as1 __attribute__((address_space(1)));
typedef unsigned int uint_as3 __attribute__((address_space(3)));

__device__ __forceinline__ float bf2f(u16 u) {
  union { unsigned int i; float f; } x; x.i = ((unsigned int)u) << 16; return x.f;
}
__device__ __forceinline__ u16 f2bf(float f) {  // round-to-nearest-even
  union { float f; unsigned int i; } x; x.f = f;
  unsigned int r = x.i + 0x7fffu + ((x.i >> 16) & 1u);
  return (u16)(r >> 16);
}
__device__ __forceinline__ void gl2lds16(const void* g, void* l) {
  // async 16B/lane global->LDS; LDS dst = wave-uniform base + lane*16
  __builtin_amdgcn_global_load_lds((uint_as1*)(uintptr_t)g,
                                   (uint_as3*)(uintptr_t)l, 16, 0, 0);
}

// C[M,N] = alpha * A[M,K] @ B[N,K]^T  (bf16 row-major, lda=ldb=K).
// Tile TM x 128, K-chunk 32*NK per barrier (m97 LDS sub-layout per 32-slab).
// EPI 0: fp32 store at Cf + blockIdx.z*zstride (split-K partials / plain)
// EPI 1: bf16 store to Cb
// EPI 2: fp32 store Cf = alpha*acc + beta*bf2f(Yb[idx])
// EPI 3: bf16 store Cb = f2bf(alpha*acc + beta*bf2f(Yb[idx]))
template<int TM, int NK, int EPI>
__global__ __launch_bounds__(256, 2)
void gemm_lds(const u16* __restrict__ A, const u16* __restrict__ B,
              float* __restrict__ Cf, u16* __restrict__ Cb,
              const u16* __restrict__ Yb, float alpha, float beta,
              int K, int ldc, int kc, long zstride)
{
  constexpr int FM  = TM / 32;   // A frags per wave
  constexpr int RPW = TM / 4;    // A rows staged per wave
  __shared__ u16 As[TM * 32 * NK];
  __shared__ u16 Bs[128 * 32 * NK];
  const int tid = threadIdx.x, w = tid >> 6, lane = tid & 63;
  const int lm = lane & 15, quad = lane >> 4;
  const int wm = w & 1, wn = w >> 1;
  const int m0 = blockIdx.x * TM, n0 = blockIdx.y * 128;
  const long k0 = (long)blockIdx.z * kc;
  const int r = lane >> 2, q = lane & 3;
  const u16* Ag = A + (long)(m0 + w * RPW + r) * K + k0 + q * 8;
  const u16* Bg = B + (long)(n0 + w * 32 + r) * K + k0 + q * 8;
  u16* Asl = As + w * RPW * 32;   // wave-uniform stage bases
  u16* Bsl = Bs + w * 1024;

  f32x4 acc[FM][4] = {};

  for (int kk = 0; kk < kc; kk += 32 * NK) {
#pragma unroll
    for (int h = 0; h < NK; ++h) {
#pragma unroll
      for (int l = 0; l < RPW / 16; ++l)
        gl2lds16(Ag + (long)(l * 16) * K + kk + h * 32,
                 Asl + h * TM * 32 + l * 512);
      gl2lds16(Bg + kk + h * 32, Bsl + h * 4096);
      gl2lds16(Bg + 16 * (long)K + kk + h * 32, Bsl + h * 4096 + 512);
    }
    __syncthreads();
#pragma unroll
    for (int h = 0; h < NK; ++h) {
      bf16x8 af[FM], bv[4];
#pragma unroll
      for (int i = 0; i < FM; ++i)
        af[i] = *(const bf16x8*)(As + h * TM * 32 +
                                 (wm * (TM / 2) + i * 16 + lm) * 32 + quad * 8);
#pragma unroll
      for (int j = 0; j < 4; ++j)
        bv[j] = *(const bf16x8*)(Bs + h * 4096 +
                                 (wn * 64 + j * 16 + lm) * 32 + quad * 8);
#pragma unroll
      for (int i = 0; i < FM; ++i)
#pragma unroll
        for (int j = 0; j < 4; ++j)
          acc[i][j] = __builtin_amdgcn_mfma_f32_16x16x32_bf16(af[i], bv[j],
                                                              acc[i][j], 0, 0, 0);
    }
    __syncthreads();
  }

  // C/D layout (m89-verified): col = lane&15, row = quad*4 + reg
  const int rbase = m0 + wm * (TM / 2) + quad * 4;
  const int cbase = n0 + wn * 64 + lm;
  const long zoff = (long)blockIdx.z * zstride;
#pragma unroll
  for (int i = 0; i < FM; ++i)
#pragma unroll
    for (int j = 0; j < 4; ++j) {
      const int col = cbase + j * 16;
#pragma unroll
      for (int rr = 0; rr < 4; ++rr) {
        const long idx = (long)(rbase + i * 16 + rr) * ldc + col;
        const float v = alpha * acc[i][j][rr];
        if constexpr (EPI == 0)      Cf[zoff + idx] = v;
        else if constexpr (EPI == 1) Cb[idx] = f2bf(v);
        else if constexpr (EPI == 2) Cf[idx] = v + beta * bf2f(Yb[idx]);
        else                         Cb[idx] = f2bf(v + beta * bf2f(Yb[idx]));
      }
    }
}

// Fused prep: tb = bf16(t - b) [8192,3072]  (blocks 0..24575)
//             WTb = bf16(W)^T [768,3072] via LDS-tiled transpose, coalesced
//             both sides; Wb = bf16(W) [3072,768] straight convert
//             (blocks 24576..25151; 48 x 12 tiles of 64x64)
__global__ void conv_all(const float* __restrict__ t, const float* __restrict__ bias,
                         const float* __restrict__ W, u16* __restrict__ tb,
                         u16* __restrict__ WTb, u16* __restrict__ Wb)
{
  __shared__ u16 lds[64 * 72];              // [i_local][o_local], stride 72
  const int bx = blockIdx.x, tid = threadIdx.x;
  if (bx < 24576) {                         // t: 6,291,456 float4
    const long i4 = (long)bx * 256 + tid;
    const float4 v = ((const float4*)t)[i4];
    const float4 bb = ((const float4*)bias)[(int)(i4 % 768)];
    ushort4 o;
    o.x = f2bf(v.x - bb.x); o.y = f2bf(v.y - bb.y);
    o.z = f2bf(v.z - bb.z); o.w = f2bf(v.w - bb.w);
    ((ushort4*)tb)[i4] = o;
  } else {
    const int bt = bx - 24576;              // tile (to, ti): o0 = to*64, i0 = ti*64
    const int o0 = (bt / 12) * 64, i0 = (bt % 12) * 64;
    const int ol = tid >> 2, cg = tid & 3;  // 64 o-rows, 4 col-groups
#pragma unroll
    for (int p = 0; p < 4; ++p) {           // 16 float4 per o-row
      const float4 v = *(const float4*)(W + (long)(o0 + ol) * 768 + i0 + (cg + p * 4) * 4);
      const int ib = (cg + p * 4) * 4;
      lds[(ib + 0) * 72 + ol] = f2bf(v.x);
      lds[(ib + 1) * 72 + ol] = f2bf(v.y);
      lds[(ib + 2) * 72 + ol] = f2bf(v.z);
      lds[(ib + 3) * 72 + ol] = f2bf(v.w);
      ushort4 wo;
      wo.x = f2bf(v.x); wo.y = f2bf(v.y); wo.z = f2bf(v.z); wo.w = f2bf(v.w);
      ((ushort4*)(Wb + (long)(o0 + ol) * 768 + i0))[cg + p * 4] = wo;
    }
    __syncthreads();
    const int cl = tid >> 2, og = tid & 3;  // 64 i-rows, 4 o-groups of 16
    const u16* src = lds + cl * 72 + og * 16;
    u16* dst = WTb + (long)(i0 + cl) * 3072 + o0 + og * 16;
    ((ushort4*)dst)[0] = ((const ushort4*)src)[0];
    ((ushort4*)dst)[1] = ((const ushort4*)src)[1];
    ((ushort4*)dst)[2] = ((const ushort4*)src)[2];
    ((ushort4*)dst)[3] = ((const ushort4*)src)[3];
  }
}

// Ef = sum_{z<6} R[z];  Eb = bf16(Ef)   (147456 float4)
__global__ void red_e(const float* __restrict__ R, float* __restrict__ Ef,
                      u16* __restrict__ Eb)
{
  const int i4 = blockIdx.x * 256 + threadIdx.x;
  float4 s = make_float4(0.f, 0.f, 0.f, 0.f);
#pragma unroll
  for (int z = 0; z < 6; ++z) {
    const float4 p = ((const float4*)R)[(long)z * 147456 + i4];
    s.x += p.x; s.y += p.y; s.z += p.z; s.w += p.w;
  }
  ((float4*)Ef)[i4] = s;
  ushort4 o; o.x = f2bf(s.x); o.y = f2bf(s.y); o.z = f2bf(s.z); o.w = f2bf(s.w);
  ((ushort4*)Eb)[i4] = o;
}

// Spb = bf16(-45*Ef + 120*sum_{z<6} R[z])   (R holds E^2 partials here)
__global__ void red_s(const float* __restrict__ R, const float* __restrict__ Ef,
                      u16* __restrict__ Spb)
{
  const int i4 = blockIdx.x * 256 + threadIdx.x;
  float4 s = make_float4(0.f, 0.f, 0.f, 0.f);
#pragma unroll
  for (int z = 0; z < 6; ++z) {
    const float4 p = ((const float4*)R)[(long)z * 147456 + i4];
    s.x += p.x; s.y += p.y; s.z += p.z; s.w += p.w;
  }
  const float4 e = ((const float4*)Ef)[i4];
  ushort4 o;
  o.x = f2bf(-45.f * e.x + 120.f * s.x);
  o.y = f2bf(-45.f * e.y + 120.f * s.y);
  o.z = f2bf(-45.f * e.z + 120.f * s.z);
  o.w = f2bf(-45.f * e.w + 120.f * s.w);
  ((ushort4*)Spb)[i4] = o;
}

extern "C" void kernel_launch(void* const* d_in, const int* in_sizes, int n_in,
                              void* d_out, int out_size, void* d_ws, size_t ws_size,
                              hipStream_t stream)
{
  const float* t    = (const float*)d_in[0];   // [8,1024,3072]
  const float* W    = (const float*)d_in[1];   // [3072,768]
  const float* bias = (const float*)d_in[2];   // [3072]
  float* out = (float*)d_out;                  // [8192,768] fp32

  char* p = (char*)d_ws;                       // 78,643,200 B used (< proven 79.8MB)
  u16*   tb   = (u16*)(p + 0);                 // 50,331,648  bf16 t-b  [8192,3072]
  u16*   WTb  = (u16*)(p + 50331648);          //  4,718,592  bf16 W^T  [768,3072]
  u16*   Wb   = (u16*)(p + 55050240);          //  4,718,592  bf16 W    [3072,768]
  float* Ef   = (float*)(p + 59768832);        //  2,359,296  E fp32    [768,768]
  u16*   Eb   = (u16*)(p + 62128128);          //  1,179,648  bf16 E
  u16*   Spb  = (u16*)(p + 63307776);          //  1,179,648  bf16 S''
  float* R    = (float*)(p + 64487424);        // 14,155,776  partials [6][768^2]
  u16*   WMTb = (u16*)(p + 64487424);          //  4,718,592  bf16 WMT [768,3072]
                                               // (WMTb aliases R: R live steps 2-5,
                                               //  WMTb live steps 6-7 — disjoint)
  const float lr = 0.001f;

  // 1. tb + WTb + Wb (LDS-tiled transpose; straight bf16 copy of W)
  conv_all<<<25152, 256, 0, stream>>>(t, bias, W, tb, WTb, Wb);
  // 2. E partials = lr * WT @ WT^T : K=3072, z=6, kc=512 (8 iters @BK64),
  //    grid 432 blocks (~1.7/CU) to overlap serial-iter latency
  gemm_lds<64, 2, 0><<<dim3(12, 6, 6), 256, 0, stream>>>(
      WTb, WTb, R, nullptr, nullptr, lr, 0.f, 3072, 768, 512, 589824);
  // 3. Ef = sum(R); Eb = bf16(Ef)
  red_e<<<576, 256, 0, stream>>>(R, Ef, Eb);
  // 4. E^2 partials = Eb @ Eb^T (E symmetric): K=768, z=6, kc=128 (2 iters)
  gemm_lds<64, 2, 0><<<dim3(12, 6, 6), 256, 0, stream>>>(
      Eb, Eb, R, nullptr, nullptr, 1.f, 0.f, 768, 768, 128, 589824);
  // 5. Spb = bf16(-45E + 120E^2)
  red_s<<<576, 256, 0, stream>>>(R, Ef, Spb);
  // 6. WMT = bf16(lr * S'' @ W^T + 0.01 * WT) : M=768, N=3072, K=768,
  //    grid 12x24=288 blocks, 12 iters (S'' symmetric => Spb row-major = S'')
  gemm_lds<64, 2, 3><<<dim3(12, 24, 1), 256, 0, stream>>>(
      Spb, Wb, nullptr, WMTb, WTb, lr, 0.01f, 768, 3072, 768, 0);
  // 7. BIG GEMM: out = tb @ WMT^T : M=8192, N=768, K=3072, fp32 direct out.
  //    TM=64 => grid 128x6=768 blocks = 3 blocks/CU (occupancy fix; m102 curve).
  //    A-panel sharers (same x, y=0..5) are 128 apart => same XCD mod 8: free L2 reuse.
  gemm_lds<64, 2, 0><<<dim3(128, 6, 1), 256, 0, stream>>>(
      tb, WMTb, out, nullptr, nullptr, 1.f, 0.f, 3072, 768, 3072, 0);
}